// Round 11
// baseline (159.467 us; speedup 1.0000x reference)
//
#include <hip/hip_runtime.h>
#include <hip/hip_bf16.h>

// SelfAttention B=4 S=2048 D=1024:
//   out = softmax((xWq^T+bq)(xWk^T+bk)^T / 32) (xWv^T+bv)
// Round-10 structure (softmax folded into QK^T epilogue + PV normalization)
// with ONE change: gemm8ph epilogue stores P' via LDS transpose (As/Bs are
// dead after the K-loop) -> bf16x8 coalesced stores instead of 128 scalar
// 2-byte stores/thread. Main loops of all GEMMs byte-identical to round 10.
// ws: xb[8192*1024]bf16 | wq,wk,wv[1024^2]bf16 | qb,kb[8192*1024]bf16 |
//     vtb[4][1024][2048]bf16 | partials[4][32][2048]f32 | sc[nb][2048^2]bf16

typedef __hip_bfloat16 bf16;
typedef __attribute__((ext_vector_type(8))) short bf16x8;
typedef __attribute__((ext_vector_type(4))) float f32x4;
typedef __attribute__((ext_vector_type(4))) short short4v;

__device__ __forceinline__ void gload16(const bf16* g, bf16* l) {
  __builtin_amdgcn_global_load_lds(
      (const __attribute__((address_space(1))) void*)g,
      (__attribute__((address_space(3))) void*)l, 16, 0, 0);
}

#define WAITV(N) asm volatile("s_waitcnt vmcnt(" #N ")" ::: "memory")
#define LGKM0    asm volatile("s_waitcnt lgkmcnt(0)" ::: "memory")
#define SCHED0   __builtin_amdgcn_sched_barrier(0)
#define BAR      __builtin_amdgcn_s_barrier()
#define PRIO1    __builtin_amdgcn_s_setprio(1)
#define PRIO0    __builtin_amdgcn_s_setprio(0)

// one dispatch for all casts: blocks [0,8192) -> x, [8192,11264) -> Wq/Wk/Wv
__global__ __launch_bounds__(256)
void cast_all(const float* __restrict__ x, const float* __restrict__ wq,
              const float* __restrict__ wk, const float* __restrict__ wv,
              bf16* __restrict__ xb, bf16* __restrict__ wb) {
  const long bid = blockIdx.x;
  const float* src;
  bf16* dst;
  long base;
  if (bid < 8192) {
    src = x; dst = xb; base = bid << 10;
  } else {
    const int j = (int)bid - 8192;
    const int w = j >> 10;
    src = (w == 0) ? wq : (w == 1) ? wk : wv;
    dst = wb + ((long)w << 20);
    base = (long)(j & 1023) << 10;
  }
  const long i = base + (long)threadIdx.x * 4;
  float4 f = *(const float4*)(src + i);
  bf16 tmp[4];
  tmp[0] = __float2bfloat16(f.x);
  tmp[1] = __float2bfloat16(f.y);
  tmp[2] = __float2bfloat16(f.z);
  tmp[3] = __float2bfloat16(f.w);
  *(short4v*)(dst + i) = *(short4v*)tmp;
}

// ===== QKV: proven 4-wave 128x128 tile, BK=64, 3 blocks/CU, ~894 TF =====
__global__ __launch_bounds__(256, 3)
void gemm_qkv(const bf16* __restrict__ A, const bf16* __restrict__ Bt,
              const float* __restrict__ b0, const float* __restrict__ b1,
              const float* __restrict__ b2, void* __restrict__ Cout,
              int K, int lda, int ldb, long sB)
{
  __shared__ __align__(16) bf16 As[128 * 64];
  __shared__ __align__(16) bf16 Bs[128 * 64];
  const int tid = threadIdx.x;
  const int z = blockIdx.z;
  const bf16* Ab = A;
  const bf16* Bb = Bt + (long)z * sB;
  const long bm = (long)blockIdx.x * 128;
  const long bn = (long)blockIdx.y * 128;
  const int wid = tid >> 6, lane = tid & 63;
  const int wr = (wid >> 1) * 64, wc = (wid & 1) * 64;
  const int l15 = lane & 15, kg = lane >> 4;

  f32x4 acc[4][4];
#pragma unroll
  for (int m = 0; m < 4; ++m)
#pragma unroll
    for (int n = 0; n < 4; ++n) acc[m][n] = (f32x4){0.f, 0.f, 0.f, 0.f};

  for (int k0 = 0; k0 < K; k0 += 64) {
#pragma unroll
    for (int i = 0; i < 4; ++i) {
      const int c = (i << 8) + tid;
      const int r = c >> 3;
      const int j = (c & 7) ^ (r & 7);
      const int ldsch = (i << 8) + (wid << 6);
      gload16(Ab + (long)(bm + r) * lda + k0 + (j << 3), As + ldsch * 8);
      gload16(Bb + (long)(bn + r) * ldb + k0 + (j << 3), Bs + ldsch * 8);
    }
    __syncthreads();
#pragma unroll
    for (int kk = 0; kk < 2; ++kk) {
      bf16x8 af[4], bfv[4];
#pragma unroll
      for (int m = 0; m < 4; ++m) {
        const int row_l = wr + (m << 4) + l15;
        const int js = ((kk << 2) + kg) ^ (row_l & 7);
        af[m] = *(const bf16x8*)&As[(row_l << 6) + (js << 3)];
      }
#pragma unroll
      for (int n = 0; n < 4; ++n) {
        const int row_l = wc + (n << 4) + l15;
        const int js = ((kk << 2) + kg) ^ (row_l & 7);
        bfv[n] = *(const bf16x8*)&Bs[(row_l << 6) + (js << 3)];
      }
#pragma unroll
      for (int m = 0; m < 4; ++m)
#pragma unroll
        for (int n = 0; n < 4; ++n)
          acc[m][n] = __builtin_amdgcn_mfma_f32_16x16x32_bf16(
              af[m], bfv[n], acc[m][n], 0, 0, 0);
    }
    __syncthreads();
  }

#pragma unroll
  for (int m = 0; m < 4; ++m) {
    const long row0 = bm + wr + (m << 4) + (kg << 2);
#pragma unroll
    for (int n = 0; n < 4; ++n) {
      const long col = bn + wc + (n << 4) + l15;
      const float* bias = (z == 0) ? b0 : (z == 1) ? b1 : b2;
      const float bias_v = bias[col];
      if (z < 2) {
        bf16* C = (bf16*)Cout + (long)z * 8192 * 1024;
#pragma unroll
        for (int rr = 0; rr < 4; ++rr)
          C[(row0 + rr) * 1024 + col] = __float2bfloat16(acc[m][n][rr] + bias_v);
      } else {
        bf16* C = (bf16*)Cout + 2L * 8192 * 1024;  // vtb
        const long bb = row0 >> 11;
        const long s0 = row0 & 2047;
        bf16 tmp[4];
#pragma unroll
        for (int rr = 0; rr < 4; ++rr)
          tmp[rr] = __float2bfloat16(acc[m][n][rr] + bias_v);
        *(short4v*)&C[(bb * 1024 + col) * 2048 + s0] = *(short4v*)tmp;
      }
    }
  }
}

// ===== QK^T: 8-phase 256x256 (main loop verbatim from round 9/10) =====
// Epilogue: e = exp(acc*scale); shfl row-sum partials (unchanged); P' stored
// via LDS transpose (As/Bs dead after loop) -> bf16x8 coalesced stores.
__global__ __launch_bounds__(512)
void gemm8ph(const bf16* __restrict__ A, const bf16* __restrict__ Bt,
             bf16* __restrict__ Cout, float* __restrict__ partials,
             int K, int lda, int ldb, int ldc, float scale,
             long sA, long sB, long sC)
{
  __shared__ __align__(16) bf16 As[2][2][128 * 64];
  __shared__ __align__(16) bf16 Bs[2][2][128 * 64];
  const int tid = threadIdx.x;
  const int wid = tid >> 6, lane = tid & 63;
  const int l15 = lane & 15, kg = lane >> 4;
  const int wr = wid >> 2;       // A-half (128-row block)
  const int wc = wid & 3;        // 64-col block
  const int bh = wc >> 1;        // B-half this wave reads
  const int z = blockIdx.z;
  const bf16* Ab = A + (long)z * sA;
  const bf16* Bb = Bt + (long)z * sB;
  const long bm = (long)blockIdx.x * 256;
  const long bn = (long)blockIdx.y * 256;

  const bf16* gAp[2][2];
  const bf16* gBp[2][2];
  int dOff[2];
#pragma unroll
  for (int l = 0; l < 2; ++l) {
    const int c = (l << 9) + tid;
    const int r = c >> 3;
    const int j = (c & 7) ^ (r & 7);
#pragma unroll
    for (int h = 0; h < 2; ++h) {
      gAp[h][l] = Ab + (long)(bm + h * 128 + r) * lda + (j << 3);
      gBp[h][l] = Bb + (long)(bn + h * 128 + r) * ldb + (j << 3);
    }
    dOff[l] = (((l << 9) + (wid << 6)) << 3);
  }
#define STG_A(H, BUF, TT) do { const int _k = (TT) << 6;            \
    gload16(gAp[H][0] + _k, &As[BUF][H][dOff[0]]);                  \
    gload16(gAp[H][1] + _k, &As[BUF][H][dOff[1]]); } while (0)
#define STG_B(H, BUF, TT) do { const int _k = (TT) << 6;            \
    gload16(gBp[H][0] + _k, &Bs[BUF][H][dOff[0]]);                  \
    gload16(gBp[H][1] + _k, &Bs[BUF][H][dOff[1]]); } while (0)

  bf16x8 af[2][4], bv[2][2][2];
  f32x4 acc[8][4];
#pragma unroll
  for (int m = 0; m < 8; ++m)
#pragma unroll
    for (int n = 0; n < 4; ++n) acc[m][n] = (f32x4){0.f, 0.f, 0.f, 0.f};

#define READA(MH, BUF) do { _Pragma("unroll") for (int kk = 0; kk < 2; ++kk) \
    _Pragma("unroll") for (int mi = 0; mi < 4; ++mi) {                       \
      const int row = (MH) * 64 + mi * 16 + l15;                             \
      const int js = ((kk << 2) + kg) ^ (row & 7);                           \
      af[kk][mi] = *(const bf16x8*)&As[BUF][wr][(row << 6) + (js << 3)];     \
    } } while (0)
#define READB(NH, BUF) do { _Pragma("unroll") for (int kk = 0; kk < 2; ++kk) \
    _Pragma("unroll") for (int ni = 0; ni < 2; ++ni) {                       \
      const int row = (wc & 1) * 64 + ((NH) * 2 + ni) * 16 + l15;            \
      const int js = ((kk << 2) + kg) ^ (row & 7);                           \
      bv[NH][kk][ni] = *(const bf16x8*)&Bs[BUF][bh][(row << 6) + (js << 3)]; \
    } } while (0)
#define MFMAQ(MH, NH) do { _Pragma("unroll") for (int kk = 0; kk < 2; ++kk)  \
    _Pragma("unroll") for (int mi = 0; mi < 4; ++mi)                         \
    _Pragma("unroll") for (int ni = 0; ni < 2; ++ni)                         \
      acc[(MH)*4+mi][(NH)*2+ni] = __builtin_amdgcn_mfma_f32_16x16x32_bf16(   \
          af[kk][mi], bv[NH][kk][ni], acc[(MH)*4+mi][(NH)*2+ni], 0, 0, 0);   \
  } while (0)

  const int T = K >> 6;  // 16 (K=1024)
  STG_B(0, 0, 0); STG_B(1, 0, 0); STG_A(0, 0, 0); STG_A(1, 0, 0);
  STG_B(0, 1, 1); STG_B(1, 1, 1);
  WAITV(4); BAR;

  for (int t = 0; t < T; t += 2) {
    const bool pre = (t + 2) < T;
    READA(0, 0); READB(0, 0);
    STG_A(0, 1, t + 1);
    BAR; LGKM0; SCHED0; PRIO1; MFMAQ(0, 0); PRIO0; BAR;
    READB(1, 0);
    STG_A(1, 1, t + 1);
    BAR; LGKM0; SCHED0; PRIO1; MFMAQ(0, 1); PRIO0; BAR;
    READA(1, 0);
    if (pre) STG_B(0, 0, t + 2);
    BAR; LGKM0; SCHED0; PRIO1; MFMAQ(1, 0); PRIO0; BAR;
    if (pre) { STG_B(1, 0, t + 2); WAITV(4); } else { WAITV(0); }
    BAR; PRIO1; MFMAQ(1, 1); PRIO0; BAR;
    READA(0, 1); READB(0, 1);
    if (pre) STG_A(0, 0, t + 2);
    BAR; LGKM0; SCHED0; PRIO1; MFMAQ(0, 0); PRIO0; BAR;
    READB(1, 1);
    if (pre) STG_A(1, 0, t + 2);
    BAR; LGKM0; SCHED0; PRIO1; MFMAQ(0, 1); PRIO0; BAR;
    READA(1, 1);
    if (pre) STG_B(0, 1, t + 3);
    BAR; LGKM0; SCHED0; PRIO1; MFMAQ(1, 0); PRIO0; BAR;
    if (pre) { STG_B(1, 1, t + 3); WAITV(4); }
    BAR; PRIO1; MFMAQ(1, 1); PRIO0; BAR;
  }
#undef STG_A
#undef STG_B
#undef READA
#undef READB
#undef MFMAQ

  // ---- epilogue ----
  // (1) exp + row-sum partials from registers (unchanged math/order), with
  //     bf16 P' values parked in LDS at [localrow][col] (As/Bs are dead:
  //     wave wr==0 -> rows 0..127 in As-flat, wr==1 -> rows 128..255 in Bs).
  float* pslice = partials + ((long)z * 32 + (long)blockIdx.y * 4 + wc) * 2048;
  bf16* flat = (wr == 0) ? (bf16*)As : (bf16*)Bs;  // [128][256] bf16
#pragma unroll
  for (int m = 0; m < 8; ++m) {
    const int lr0 = m * 16 + (kg << 2);          // local row in wave half
    const long row0 = bm + wr * 128 + lr0;
    float rs[4] = {0.f, 0.f, 0.f, 0.f};
#pragma unroll
    for (int n = 0; n < 4; ++n) {
      const int lcol = wc * 64 + n * 16 + l15;
#pragma unroll
      for (int rr = 0; rr < 4; ++rr) {
        const float e = __expf(acc[m][n][rr] * scale);
        rs[rr] += e;
        flat[(lr0 + rr) * 256 + lcol] = __float2bfloat16(e);
      }
    }
#pragma unroll
    for (int rr = 0; rr < 4; ++rr) {
      float p = rs[rr];
      p += __shfl_xor(p, 1);
      p += __shfl_xor(p, 2);
      p += __shfl_xor(p, 4);
      p += __shfl_xor(p, 8);
      if (l15 == 0) pslice[row0 + rr] = p;
    }
  }
  __syncthreads();
  // (2) coalesced P' store: 256x256 bf16 tile = 8192 16B-chunks, 16/thread.
  bf16* Cz = Cout + (long)z * sC;
  const bf16* fA = (const bf16*)As;
  const bf16* fB = (const bf16*)Bs;
#pragma unroll
  for (int i = 0; i < 16; ++i) {
    const int c = (i << 9) + tid;    // 0..8191
    const int r = c >> 5;            // tile row 0..255
    const int j = c & 31;            // 16B chunk in row
    const bf16x8 v = (r < 128)
        ? *(const bf16x8*)(fA + r * 256 + (j << 3))
        : *(const bf16x8*)(fB + (r - 128) * 256 + (j << 3));
    *(bf16x8*)&Cz[(bm + r) * ldc + bn + (j << 3)] = v;
  }
}

// ===== PV: proven 8-wave 128x128, 56.5 KB LDS -> 2 blocks/CU =====
__global__ __launch_bounds__(512, 4)
void gemm_pv(const bf16* __restrict__ A, const bf16* __restrict__ Bt,
             float* __restrict__ Cout, const float* __restrict__ psums,
             int K, int lda, int ldb, int ldc, long sA, long sB, long sC)
{
  __shared__ __align__(16) bf16 As[128 * 64 + 6144];
  __shared__ __align__(16) bf16 Bs[128 * 64 + 6144];
  __shared__ float inv_sum[128];
  const int tid = threadIdx.x;
  const int z = blockIdx.z;
  const bf16* Ab = A + (long)z * sA;
  const bf16* Bb = Bt + (long)z * sB;
  const long bm = (long)blockIdx.x * 128;
  const long bn = (long)blockIdx.y * 128;
  const int wid = tid >> 6, lane = tid & 63;
  const int wr = (wid >> 2) * 64, wc = (wid & 3) * 32;
  const int l15 = lane & 15, kg = lane >> 4;

  if (tid < 128) {
    const float* ps = psums + (long)z * 32 * 2048 + bm + tid;
    float s = 0.f;
#pragma unroll
    for (int i = 0; i < 32; ++i) s += ps[(long)i * 2048];
    inv_sum[tid] = 1.0f / s;
  }

  f32x4 acc[4][2];
#pragma unroll
  for (int m = 0; m < 4; ++m)
#pragma unroll
    for (int n = 0; n < 2; ++n) acc[m][n] = (f32x4){0.f, 0.f, 0.f, 0.f};

  for (int k0 = 0; k0 < K; k0 += 64) {
#pragma unroll
    for (int i = 0; i < 2; ++i) {
      const int c = (i << 9) + tid;
      const int r = c >> 3;
      const int j = (c & 7) ^ (r & 7);
      const int ldsch = (i << 9) + (wid << 6);
      gload16(Ab + (long)(bm + r) * lda + k0 + (j << 3), As + ldsch * 8);
      gload16(Bb + (long)(bn + r) * ldb + k0 + (j << 3), Bs + ldsch * 8);
    }
    __syncthreads();
#pragma unroll
    for (int kk = 0; kk < 2; ++kk) {
      bf16x8 af[4], bfv[2];
#pragma unroll
      for (int m = 0; m < 4; ++m) {
        const int row_l = wr + (m << 4) + l15;
        const int js = ((kk << 2) + kg) ^ (row_l & 7);
        af[m] = *(const bf16x8*)&As[(row_l << 6) + (js << 3)];
      }
#pragma unroll
      for (int n = 0; n < 2; ++n) {
        const int row_l = wc + (n << 4) + l15;
        const int js = ((kk << 2) + kg) ^ (row_l & 7);
        bfv[n] = *(const bf16x8*)&Bs[(row_l << 6) + (js << 3)];
      }
#pragma unroll
      for (int m = 0; m < 4; ++m)
#pragma unroll
        for (int n = 0; n < 2; ++n)
          acc[m][n] = __builtin_amdgcn_mfma_f32_16x16x32_bf16(
              af[m], bfv[n], acc[m][n], 0, 0, 0);
    }
    __syncthreads();
  }

#pragma unroll
  for (int m = 0; m < 4; ++m) {
    const int lr = wr + (m << 4) + (kg << 2);
    const long row0 = bm + lr;
#pragma unroll
    for (int n = 0; n < 2; ++n) {
      const long col = bn + wc + (n << 4) + l15;
      float* C = Cout + (long)z * sC;
#pragma unroll
      for (int rr = 0; rr < 4; ++rr)
        C[(row0 + rr) * ldc + col] = acc[m][n][rr] * inv_sum[lr + rr];
    }
  }
}

extern "C" void kernel_launch(void* const* d_in, const int* in_sizes, int n_in,
                              void* d_out, int out_size, void* d_ws, size_t ws_size,
                              hipStream_t stream) {
  const float* x  = (const float*)d_in[0];
  const float* Wq = (const float*)d_in[1];
  const float* bq = (const float*)d_in[2];
  const float* Wk = (const float*)d_in[3];
  const float* bk = (const float*)d_in[4];
  const float* Wv = (const float*)d_in[5];
  const float* bv = (const float*)d_in[6];
  float* out = (float*)d_out;

  const int B = 4, S = 2048, D = 1024;
  const int M = B * S;  // 8192

  bf16* xb   = (bf16*)d_ws;
  bf16* wqb  = xb + (size_t)M * D;
  bf16* qb   = wqb + 3 * (size_t)D * D;
  bf16* kb   = qb + (size_t)M * D;
  bf16* vtb  = kb + (size_t)M * D;
  float* pts = (float*)(vtb + (size_t)M * D);   // partials [4][32][2048] f32
  bf16* sc   = (bf16*)(pts + 4L * 32 * 2048);   // bf16 P', nb batches

  size_t avail = ws_size - ((size_t)((char*)sc - (char*)d_ws));
  int nb = (int)(avail / ((size_t)S * S * 2));
  if (nb > B) nb = B;
  if (nb < 1) nb = 1;

  // all casts in one dispatch
  cast_all<<<dim3(M * D / 1024 + 3 * D * D / 1024), 256, 0, stream>>>(
      x, Wq, Wk, Wv, xb, wqb);

  // fused QKV projection, grid 64x8x3 = 1536 blocks (2 exact rounds @3/CU)
  gemm_qkv<<<dim3(M / 128, D / 128, 3), 256, 0, stream>>>(
      xb, wqb, bq, bk, bv, qb, D, D, D, (long)D * D);

  const float iscale = 1.0f / 32.0f;  // 1/sqrt(1024)
  for (int g = 0; g < B; g += nb) {
    const int gn = (g + nb <= B) ? nb : (B - g);
    // QK^T + exp + row-sum partials: grid 8x8xgn
    gemm8ph<<<dim3(S / 256, S / 256, gn), 512, 0, stream>>>(
        qb + (size_t)g * S * D, kb + (size_t)g * S * D,
        sc, pts + (size_t)g * 32 * 2048,
        D, D, D, S, iscale, (long)S * D, (long)S * D, (long)S * S);
    // PV + 1/sum normalization: grid 16x8xgn
    gemm_pv<<<dim3(S / 128, D / 128, gn), 512, 0, stream>>>(
        sc, vtb + (size_t)g * D * S,
        out + (size_t)g * S * D, pts + (size_t)g * 32 * 2048,
        S, S, S, D, (long)S * S, (long)D * S, (long)S * D);
  }
}

// Round 12
// 158.212 us; speedup vs baseline: 1.0079x; 1.0079x over previous
//
#include <hip/hip_runtime.h>
#include <hip/hip_bf16.h>

// SelfAttention B=4 S=2048 D=1024:
//   out = softmax((xWq^T+bq)(xWk^T+bk)^T / 32) (xWv^T+bv)
// FINAL (= round-10 measured best, 156.7 us): softmax folded into QK^T
// epilogue (exp from fp32 acc + deterministic shfl row-sum partials) + PV
// 1/sum normalization. GEMMs: session-proven m97-structure kernels
// (chunk-XOR LDS swizzle = 0 bank conflicts, global_load_lds width-16).
// ws: xb[8192*1024]bf16 | wq,wk,wv[1024^2]bf16 | qb,kb[8192*1024]bf16 |
//     vtb[4][1024][2048]bf16 | partials[4][32][2048]f32 | sc[nb][2048^2]bf16

typedef __hip_bfloat16 bf16;
typedef __attribute__((ext_vector_type(8))) short bf16x8;
typedef __attribute__((ext_vector_type(4))) float f32x4;
typedef __attribute__((ext_vector_type(4))) short short4v;

__device__ __forceinline__ void gload16(const bf16* g, bf16* l) {
  __builtin_amdgcn_global_load_lds(
      (const __attribute__((address_space(1))) void*)g,
      (__attribute__((address_space(3))) void*)l, 16, 0, 0);
}

#define WAITV(N) asm volatile("s_waitcnt vmcnt(" #N ")" ::: "memory")
#define LGKM0    asm volatile("s_waitcnt lgkmcnt(0)" ::: "memory")
#define SCHED0   __builtin_amdgcn_sched_barrier(0)
#define BAR      __builtin_amdgcn_s_barrier()
#define PRIO1    __builtin_amdgcn_s_setprio(1)
#define PRIO0    __builtin_amdgcn_s_setprio(0)

// one dispatch for all casts: blocks [0,8192) -> x, [8192,11264) -> Wq/Wk/Wv
__global__ __launch_bounds__(256)
void cast_all(const float* __restrict__ x, const float* __restrict__ wq,
              const float* __restrict__ wk, const float* __restrict__ wv,
              bf16* __restrict__ xb, bf16* __restrict__ wb) {
  const long bid = blockIdx.x;
  const float* src;
  bf16* dst;
  long base;
  if (bid < 8192) {
    src = x; dst = xb; base = bid << 10;
  } else {
    const int j = (int)bid - 8192;
    const int w = j >> 10;
    src = (w == 0) ? wq : (w == 1) ? wk : wv;
    dst = wb + ((long)w << 20);
    base = (long)(j & 1023) << 10;
  }
  const long i = base + (long)threadIdx.x * 4;
  float4 f = *(const float4*)(src + i);
  bf16 tmp[4];
  tmp[0] = __float2bfloat16(f.x);
  tmp[1] = __float2bfloat16(f.y);
  tmp[2] = __float2bfloat16(f.z);
  tmp[3] = __float2bfloat16(f.w);
  *(short4v*)(dst + i) = *(short4v*)tmp;
}

// ===== QKV: proven 4-wave 128x128 tile, BK=64, 3 blocks/CU, ~894 TF =====
__global__ __launch_bounds__(256, 3)
void gemm_qkv(const bf16* __restrict__ A, const bf16* __restrict__ Bt,
              const float* __restrict__ b0, const float* __restrict__ b1,
              const float* __restrict__ b2, void* __restrict__ Cout,
              int K, int lda, int ldb, long sB)
{
  __shared__ __align__(16) bf16 As[128 * 64];
  __shared__ __align__(16) bf16 Bs[128 * 64];
  const int tid = threadIdx.x;
  const int z = blockIdx.z;
  const bf16* Ab = A;
  const bf16* Bb = Bt + (long)z * sB;
  const long bm = (long)blockIdx.x * 128;
  const long bn = (long)blockIdx.y * 128;
  const int wid = tid >> 6, lane = tid & 63;
  const int wr = (wid >> 1) * 64, wc = (wid & 1) * 64;
  const int l15 = lane & 15, kg = lane >> 4;

  f32x4 acc[4][4];
#pragma unroll
  for (int m = 0; m < 4; ++m)
#pragma unroll
    for (int n = 0; n < 4; ++n) acc[m][n] = (f32x4){0.f, 0.f, 0.f, 0.f};

  for (int k0 = 0; k0 < K; k0 += 64) {
#pragma unroll
    for (int i = 0; i < 4; ++i) {
      const int c = (i << 8) + tid;
      const int r = c >> 3;
      const int j = (c & 7) ^ (r & 7);
      const int ldsch = (i << 8) + (wid << 6);
      gload16(Ab + (long)(bm + r) * lda + k0 + (j << 3), As + ldsch * 8);
      gload16(Bb + (long)(bn + r) * ldb + k0 + (j << 3), Bs + ldsch * 8);
    }
    __syncthreads();
#pragma unroll
    for (int kk = 0; kk < 2; ++kk) {
      bf16x8 af[4], bfv[4];
#pragma unroll
      for (int m = 0; m < 4; ++m) {
        const int row_l = wr + (m << 4) + l15;
        const int js = ((kk << 2) + kg) ^ (row_l & 7);
        af[m] = *(const bf16x8*)&As[(row_l << 6) + (js << 3)];
      }
#pragma unroll
      for (int n = 0; n < 4; ++n) {
        const int row_l = wc + (n << 4) + l15;
        const int js = ((kk << 2) + kg) ^ (row_l & 7);
        bfv[n] = *(const bf16x8*)&Bs[(row_l << 6) + (js << 3)];
      }
#pragma unroll
      for (int m = 0; m < 4; ++m)
#pragma unroll
        for (int n = 0; n < 4; ++n)
          acc[m][n] = __builtin_amdgcn_mfma_f32_16x16x32_bf16(
              af[m], bfv[n], acc[m][n], 0, 0, 0);
    }
    __syncthreads();
  }

#pragma unroll
  for (int m = 0; m < 4; ++m) {
    const long row0 = bm + wr + (m << 4) + (kg << 2);
#pragma unroll
    for (int n = 0; n < 4; ++n) {
      const long col = bn + wc + (n << 4) + l15;
      const float* bias = (z == 0) ? b0 : (z == 1) ? b1 : b2;
      const float bias_v = bias[col];
      if (z < 2) {
        bf16* C = (bf16*)Cout + (long)z * 8192 * 1024;
#pragma unroll
        for (int rr = 0; rr < 4; ++rr)
          C[(row0 + rr) * 1024 + col] = __float2bfloat16(acc[m][n][rr] + bias_v);
      } else {
        bf16* C = (bf16*)Cout + 2L * 8192 * 1024;  // vtb
        const long bb = row0 >> 11;
        const long s0 = row0 & 2047;
        bf16 tmp[4];
#pragma unroll
        for (int rr = 0; rr < 4; ++rr)
          tmp[rr] = __float2bfloat16(acc[m][n][rr] + bias_v);
        *(short4v*)&C[(bb * 1024 + col) * 2048 + s0] = *(short4v*)tmp;
      }
    }
  }
}

// ===== QK^T: 8-phase 256x256 + fused exp/row-sum epilogue =====
__global__ __launch_bounds__(512)
void gemm8ph(const bf16* __restrict__ A, const bf16* __restrict__ Bt,
             bf16* __restrict__ Cout, float* __restrict__ partials,
             int K, int lda, int ldb, int ldc, float scale,
             long sA, long sB, long sC)
{
  __shared__ __align__(16) bf16 As[2][2][128 * 64];
  __shared__ __align__(16) bf16 Bs[2][2][128 * 64];
  const int tid = threadIdx.x;
  const int wid = tid >> 6, lane = tid & 63;
  const int l15 = lane & 15, kg = lane >> 4;
  const int wr = wid >> 2;       // A-half (128-row block)
  const int wc = wid & 3;        // 64-col block
  const int bh = wc >> 1;        // B-half this wave reads
  const int z = blockIdx.z;
  const bf16* Ab = A + (long)z * sA;
  const bf16* Bb = Bt + (long)z * sB;
  const long bm = (long)blockIdx.x * 256;
  const long bn = (long)blockIdx.y * 256;

  const bf16* gAp[2][2];
  const bf16* gBp[2][2];
  int dOff[2];
#pragma unroll
  for (int l = 0; l < 2; ++l) {
    const int c = (l << 9) + tid;
    const int r = c >> 3;
    const int j = (c & 7) ^ (r & 7);
#pragma unroll
    for (int h = 0; h < 2; ++h) {
      gAp[h][l] = Ab + (long)(bm + h * 128 + r) * lda + (j << 3);
      gBp[h][l] = Bb + (long)(bn + h * 128 + r) * ldb + (j << 3);
    }
    dOff[l] = (((l << 9) + (wid << 6)) << 3);
  }
#define STG_A(H, BUF, TT) do { const int _k = (TT) << 6;            \
    gload16(gAp[H][0] + _k, &As[BUF][H][dOff[0]]);                  \
    gload16(gAp[H][1] + _k, &As[BUF][H][dOff[1]]); } while (0)
#define STG_B(H, BUF, TT) do { const int _k = (TT) << 6;            \
    gload16(gBp[H][0] + _k, &Bs[BUF][H][dOff[0]]);                  \
    gload16(gBp[H][1] + _k, &Bs[BUF][H][dOff[1]]); } while (0)

  bf16x8 af[2][4], bv[2][2][2];
  f32x4 acc[8][4];
#pragma unroll
  for (int m = 0; m < 8; ++m)
#pragma unroll
    for (int n = 0; n < 4; ++n) acc[m][n] = (f32x4){0.f, 0.f, 0.f, 0.f};

#define READA(MH, BUF) do { _Pragma("unroll") for (int kk = 0; kk < 2; ++kk) \
    _Pragma("unroll") for (int mi = 0; mi < 4; ++mi) {                       \
      const int row = (MH) * 64 + mi * 16 + l15;                             \
      const int js = ((kk << 2) + kg) ^ (row & 7);                           \
      af[kk][mi] = *(const bf16x8*)&As[BUF][wr][(row << 6) + (js << 3)];     \
    } } while (0)
#define READB(NH, BUF) do { _Pragma("unroll") for (int kk = 0; kk < 2; ++kk) \
    _Pragma("unroll") for (int ni = 0; ni < 2; ++ni) {                       \
      const int row = (wc & 1) * 64 + ((NH) * 2 + ni) * 16 + l15;            \
      const int js = ((kk << 2) + kg) ^ (row & 7);                           \
      bv[NH][kk][ni] = *(const bf16x8*)&Bs[BUF][bh][(row << 6) + (js << 3)]; \
    } } while (0)
#define MFMAQ(MH, NH) do { _Pragma("unroll") for (int kk = 0; kk < 2; ++kk)  \
    _Pragma("unroll") for (int mi = 0; mi < 4; ++mi)                         \
    _Pragma("unroll") for (int ni = 0; ni < 2; ++ni)                         \
      acc[(MH)*4+mi][(NH)*2+ni] = __builtin_amdgcn_mfma_f32_16x16x32_bf16(   \
          af[kk][mi], bv[NH][kk][ni], acc[(MH)*4+mi][(NH)*2+ni], 0, 0, 0);   \
  } while (0)

  const int T = K >> 6;  // 16 (K=1024)
  STG_B(0, 0, 0); STG_B(1, 0, 0); STG_A(0, 0, 0); STG_A(1, 0, 0);
  STG_B(0, 1, 1); STG_B(1, 1, 1);
  WAITV(4); BAR;

  for (int t = 0; t < T; t += 2) {
    const bool pre = (t + 2) < T;
    READA(0, 0); READB(0, 0);
    STG_A(0, 1, t + 1);
    BAR; LGKM0; SCHED0; PRIO1; MFMAQ(0, 0); PRIO0; BAR;
    READB(1, 0);
    STG_A(1, 1, t + 1);
    BAR; LGKM0; SCHED0; PRIO1; MFMAQ(0, 1); PRIO0; BAR;
    READA(1, 0);
    if (pre) STG_B(0, 0, t + 2);
    BAR; LGKM0; SCHED0; PRIO1; MFMAQ(1, 0); PRIO0; BAR;
    if (pre) { STG_B(1, 0, t + 2); WAITV(4); } else { WAITV(0); }
    BAR; PRIO1; MFMAQ(1, 1); PRIO0; BAR;
    READA(0, 1); READB(0, 1);
    if (pre) STG_A(0, 0, t + 2);
    BAR; LGKM0; SCHED0; PRIO1; MFMAQ(0, 0); PRIO0; BAR;
    READB(1, 1);
    if (pre) STG_A(1, 0, t + 2);
    BAR; LGKM0; SCHED0; PRIO1; MFMAQ(0, 1); PRIO0; BAR;
    READA(1, 1);
    if (pre) STG_B(0, 1, t + 3);
    BAR; LGKM0; SCHED0; PRIO1; MFMAQ(1, 0); PRIO0; BAR;
    if (pre) { STG_B(1, 1, t + 3); WAITV(4); }
    BAR; PRIO1; MFMAQ(1, 1); PRIO0; BAR;
  }
#undef STG_A
#undef STG_B
#undef READA
#undef READB
#undef MFMAQ

  // epilogue: e = exp(s); store bf16 P'; reduce row-sums over this wave's
  // 64 cols (4 n-slices in-lane + 16-lane shfl_xor tree).
  bf16* C = Cout + (long)z * sC;
  float* pslice = partials + ((long)z * 32 + (long)blockIdx.y * 4 + wc) * 2048;
#pragma unroll
  for (int m = 0; m < 8; ++m) {
    const long row0 = bm + wr * 128 + m * 16 + (kg << 2);
    float rs0 = 0.f, rs1 = 0.f, rs2 = 0.f, rs3 = 0.f;
#pragma unroll
    for (int n = 0; n < 4; ++n) {
      const long col = bn + wc * 64 + n * 16 + l15;
      const float e0 = __expf(acc[m][n][0] * scale);
      const float e1 = __expf(acc[m][n][1] * scale);
      const float e2 = __expf(acc[m][n][2] * scale);
      const float e3 = __expf(acc[m][n][3] * scale);
      C[(row0 + 0) * ldc + col] = __float2bfloat16(e0);
      C[(row0 + 1) * ldc + col] = __float2bfloat16(e1);
      C[(row0 + 2) * ldc + col] = __float2bfloat16(e2);
      C[(row0 + 3) * ldc + col] = __float2bfloat16(e3);
      rs0 += e0; rs1 += e1; rs2 += e2; rs3 += e3;
    }
    float rs[4] = {rs0, rs1, rs2, rs3};
#pragma unroll
    for (int rr = 0; rr < 4; ++rr) {
      float p = rs[rr];
      p += __shfl_xor(p, 1);
      p += __shfl_xor(p, 2);
      p += __shfl_xor(p, 4);
      p += __shfl_xor(p, 8);
      if (l15 == 0) pslice[row0 + rr] = p;
    }
  }
}

// ===== PV: proven 8-wave 128x128, 56.5 KB LDS -> 2 blocks/CU =====
__global__ __launch_bounds__(512, 4)
void gemm_pv(const bf16* __restrict__ A, const bf16* __restrict__ Bt,
             float* __restrict__ Cout, const float* __restrict__ psums,
             int K, int lda, int ldb, int ldc, long sA, long sB, long sC)
{
  __shared__ __align__(16) bf16 As[128 * 64 + 6144];
  __shared__ __align__(16) bf16 Bs[128 * 64 + 6144];
  __shared__ float inv_sum[128];
  const int tid = threadIdx.x;
  const int z = blockIdx.z;
  const bf16* Ab = A + (long)z * sA;
  const bf16* Bb = Bt + (long)z * sB;
  const long bm = (long)blockIdx.x * 128;
  const long bn = (long)blockIdx.y * 128;
  const int wid = tid >> 6, lane = tid & 63;
  const int wr = (wid >> 2) * 64, wc = (wid & 3) * 32;
  const int l15 = lane & 15, kg = lane >> 4;

  if (tid < 128) {
    const float* ps = psums + (long)z * 32 * 2048 + bm + tid;
    float s = 0.f;
#pragma unroll
    for (int i = 0; i < 32; ++i) s += ps[(long)i * 2048];
    inv_sum[tid] = 1.0f / s;
  }

  f32x4 acc[4][2];
#pragma unroll
  for (int m = 0; m < 4; ++m)
#pragma unroll
    for (int n = 0; n < 2; ++n) acc[m][n] = (f32x4){0.f, 0.f, 0.f, 0.f};

  for (int k0 = 0; k0 < K; k0 += 64) {
#pragma unroll
    for (int i = 0; i < 2; ++i) {
      const int c = (i << 9) + tid;
      const int r = c >> 3;
      const int j = (c & 7) ^ (r & 7);
      const int ldsch = (i << 9) + (wid << 6);
      gload16(Ab + (long)(bm + r) * lda + k0 + (j << 3), As + ldsch * 8);
      gload16(Bb + (long)(bn + r) * ldb + k0 + (j << 3), Bs + ldsch * 8);
    }
    __syncthreads();
#pragma unroll
    for (int kk = 0; kk < 2; ++kk) {
      bf16x8 af[4], bfv[2];
#pragma unroll
      for (int m = 0; m < 4; ++m) {
        const int row_l = wr + (m << 4) + l15;
        const int js = ((kk << 2) + kg) ^ (row_l & 7);
        af[m] = *(const bf16x8*)&As[(row_l << 6) + (js << 3)];
      }
#pragma unroll
      for (int n = 0; n < 2; ++n) {
        const int row_l = wc + (n << 4) + l15;
        const int js = ((kk << 2) + kg) ^ (row_l & 7);
        bfv[n] = *(const bf16x8*)&Bs[(row_l << 6) + (js << 3)];
      }
#pragma unroll
      for (int m = 0; m < 4; ++m)
#pragma unroll
        for (int n = 0; n < 2; ++n)
          acc[m][n] = __builtin_amdgcn_mfma_f32_16x16x32_bf16(
              af[m], bfv[n], acc[m][n], 0, 0, 0);
    }
    __syncthreads();
  }

#pragma unroll
  for (int m = 0; m < 4; ++m) {
    const int lr = wr + (m << 4) + (kg << 2);
    const long row0 = bm + lr;
#pragma unroll
    for (int n = 0; n < 2; ++n) {
      const long col = bn + wc + (n << 4) + l15;
      float* C = Cout + (long)z * sC;
#pragma unroll
      for (int rr = 0; rr < 4; ++rr)
        C[(row0 + rr) * ldc + col] = acc[m][n][rr] * inv_sum[lr + rr];
    }
  }
}

extern "C" void kernel_launch(void* const* d_in, const int* in_sizes, int n_in,
                              void* d_out, int out_size, void* d_ws, size_t ws_size,
                              hipStream_t stream) {
  const float* x  = (const float*)d_in[0];
  const float* Wq = (const float*)d_in[1];
  const float* bq = (const float*)d_in[2];
  const float* Wk = (const float*)d_in[3];
  const float* bk = (const float*)d_in[4];
  const float* Wv = (const float*)d_in[5];
  const float* bv = (const float*)d_in[6];
  float* out = (float*)d_out;

  const int B = 4, S = 2048, D = 1024;
  const int M = B * S;  // 8192

  bf16* xb   = (bf16*)d_ws;
  bf16* wqb  = xb + (size_t)M * D;
  bf16* qb   = wqb + 3 * (size_t)D * D;
  bf16* kb   = qb + (size_t)M * D;
  bf16* vtb  = kb + (size_t)M * D;
  float* pts = (float*)(vtb + (size_t)M * D);   // partials [4][32][2048] f32
  bf16* sc   = (bf16*)(pts + 4L * 32 * 2048);   // bf16 P', nb batches

  size_t avail = ws_size - ((size_t)((char*)sc - (char*)d_ws));
  int nb = (int)(avail / ((size_t)S * S * 2));
  if (nb > B) nb = B;
  if (nb < 1) nb = 1;

  // all casts in one dispatch
  cast_all<<<dim3(M * D / 1024 + 3 * D * D / 1024), 256, 0, stream>>>(
      x, Wq, Wk, Wv, xb, wqb);

  // fused QKV projection, grid 64x8x3 = 1536 blocks (2 exact rounds @3/CU)
  gemm_qkv<<<dim3(M / 128, D / 128, 3), 256, 0, stream>>>(
      xb, wqb, bq, bk, bv, qb, D, D, D, (long)D * D);

  const float iscale = 1.0f / 32.0f;  // 1/sqrt(1024)
  for (int g = 0; g < B; g += nb) {
    const int gn = (g + nb <= B) ? nb : (B - g);
    // QK^T + exp + row-sum partials: grid 8x8xgn
    gemm8ph<<<dim3(S / 256, S / 256, gn), 512, 0, stream>>>(
        qb + (size_t)g * S * D, kb + (size_t)g * S * D,
        sc, pts + (size_t)g * 32 * 2048,
        D, D, D, S, iscale, (long)S * D, (long)S * D, (long)S * S);
    // PV + 1/sum normalization: grid 16x8xgn
    gemm_pv<<<dim3(S / 128, D / 128, gn), 512, 0, stream>>>(
        sc, vtb + (size_t)g * D * S,
        out + (size_t)g * S * D, pts + (size_t)g * 32 * 2048,
        S, S, S, D, (long)S * S, (long)D * S, (long)S * D);
  }
}